// Round 5
// baseline (382.464 us; speedup 1.0000x reference)
//
#include <hip/hip_runtime.h>
#include <hip/hip_bf16.h>

// W8Linear: out[32,16384] = (x[32,4096] . W[16384,4096]^T) * scale[n] + bias[n]
// Harness dtype reality: x/scale/bias fp32 buffers (fp16 promoted); weight
// int32 (268 MB); out FLOAT32. Correct since R3 (absmax 2.0).
//
// Perf forensics (weight-read rate vs harness fill 6.6-6.7 TB/s write):
//   R6: GEMM cold 123 us = 2.2 TB/s; pipes idle (VALUBusy 5%, MfmaUtil 2.6%).
//   R7: k-phase de-lockstep            -> null.
//   R8: 4 KB contiguous runs           -> null (run length irrelevant).
//   R0: 64 KB linear + nt + 4-ch block -> 435 us (confounded regression).
//   R1: NT aux on global_load_lds      -> null (DMA aux policy irrelevant).
//   R2: 256 streams (1 blk/CU, dbuf)   -> null (stream count irrelevant).
//   R3: barrier-free per-lane direct-to-reg continuous stream -> 379 us,
//       null. READ-ISSUE STRUCTURE IS FULLY EXONERATED.
//   Surviving model: measured window contains the 1 GiB harness poison-fill;
//   its dirty lines drain through the 256 MiB MALL during our GEMM, and our
//   268 MB read-allocate sweep evicts dirty fill lines -> forced writebacks
//   interleaved with reads. 268R + ~256W mixed ~= 2.6 TB/s -> read ~2 TB/s.
//   No read-side knob touches the write drain -> all the nulls.
//
// R4 (this): single variable on R3 = __builtin_nontemporal_load on the
// WEIGHT stream only (nt = evict-first allocation -> recycles a few ways,
// does not sweep dirty fill lines to DRAM). x/scale/bias stay cached
// (x is deliberately MALL-hot). Everything else bit-identical to R3.

typedef __attribute__((ext_vector_type(4))) int    i32x4;
typedef __attribute__((ext_vector_type(4))) float  f32x4;
typedef __attribute__((ext_vector_type(8))) short  s16x8;
typedef __attribute__((ext_vector_type(8))) __bf16 bf16x8;

constexpr int K = 4096;
constexpr int N = 16384;
constexpr size_t XB_OFF = 0;              // bf16 x: 32*4096*2 = 256 KB in d_ws

// fp32 -> bf16 RNE (finite inputs).
__device__ inline unsigned short f2bf_rne(float f) {
    unsigned u = __builtin_bit_cast(unsigned, f);
    u += 0x7FFF + ((u >> 16) & 1);
    return (unsigned short)(u >> 16);
}

// 8 int32 weights -> 8 bf16, exact (|w|<=127; fp32->bf16 truncation lossless).
__device__ inline bf16x8 cvtW(i32x4 lo, i32x4 hi) {
    s16x8 r;
#pragma unroll
    for (int i = 0; i < 4; ++i) {
        r[i]     = (short)(__builtin_bit_cast(unsigned, (float)lo[i]) >> 16);
        r[i + 4] = (short)(__builtin_bit_cast(unsigned, (float)hi[i]) >> 16);
    }
    return __builtin_bit_cast(bf16x8, r);
}

// ---- k1: x fp32 -> bf16 ----------------------------------------------------
__global__ __launch_bounds__(256) void xcvt_kernel(const float* __restrict__ x,
                                                   unsigned short* __restrict__ xb) {
    const int i = (blockIdx.x * 256 + threadIdx.x) * 8;
    f32x4 lo = *reinterpret_cast<const f32x4*>(x + i);
    f32x4 hi = *reinterpret_cast<const f32x4*>(x + i + 4);
    s16x8 r;
#pragma unroll
    for (int j = 0; j < 4; ++j) {
        r[j]     = (short)f2bf_rne(lo[j]);
        r[j + 4] = (short)f2bf_rne(hi[j]);
    }
    *reinterpret_cast<s16x8*>(xb + i) = r;
}

// ---- k2: GEMM, barrier-free streaming, NT (no-allocate) weight reads -------
__global__ __launch_bounds__(256, 2) void w8gemm_kernel(
    const __bf16* __restrict__ xb,
    const int* __restrict__ w,
    const float* __restrict__ scale,
    const float* __restrict__ bias,
    float* __restrict__ out)
{
    __shared__ float red[2048];           // 8 KB, epilogue only

    const int tid  = threadIdx.x;
    const int lane = tid & 63;
    const int wave = tid >> 6;
    const int n16  = lane & 15;
    const int quad = lane >> 4;

    const int c0 = blockIdx.x * 16;       // 16 channels per block

    // Wave w owns k-ints [w*1024, (w+1)*1024) of its 16 rows: 32 MFMA k-steps.
    // Lane (n16, quad): W ints [quad*8, +8) of row c0+n16 at each step.
    const i32x4* __restrict__ wp =
        reinterpret_cast<const i32x4*>(w + (size_t)(c0 + n16) * K
                                         + wave * 1024 + quad * 8);
    const bf16x8* __restrict__ xp0 =
        reinterpret_cast<const bf16x8*>(xb + (size_t)n16 * K
                                           + wave * 1024 + quad * 8);
    const bf16x8* __restrict__ xp1 =
        reinterpret_cast<const bf16x8*>(xb + (size_t)(n16 + 16) * K
                                           + wave * 1024 + quad * 8);

    f32x4 acc0 = {0.f, 0.f, 0.f, 0.f};
    f32x4 acc1 = {0.f, 0.f, 0.f, 0.f};

    struct Frag { i32x4 b0, b1; bf16x8 x0, x1; };
    Frag A[4], B[4];

    // c is unroll-static at every call site -> all indices compile-time.
    auto loadC = [&](Frag (&f)[4], int c) {
#pragma unroll
        for (int j = 0; j < 4; ++j) {
            const int s = c * 4 + j;
            f[j].b0 = __builtin_nontemporal_load(wp + s * 8);
            f[j].b1 = __builtin_nontemporal_load(wp + s * 8 + 1);
            f[j].x0 = xp0[s * 4];
            f[j].x1 = xp1[s * 4];
        }
    };
    auto compC = [&](Frag (&f)[4]) {
#pragma unroll
        for (int j = 0; j < 4; ++j) {
            bf16x8 bf = cvtW(f[j].b0, f[j].b1);
            acc0 = __builtin_amdgcn_mfma_f32_16x16x32_bf16(f[j].x0, bf, acc0, 0, 0, 0);
            acc1 = __builtin_amdgcn_mfma_f32_16x16x32_bf16(f[j].x1, bf, acc1, 0, 0, 0);
        }
    };

    // 8 chunks of 4 k-steps, 2-deep ping-pong: while computing one chunk the
    // other chunk's 16 loads are in flight; no waitcnt-drain, no barrier.
    loadC(A, 0);
    loadC(B, 1);
#pragma unroll
    for (int cp = 0; cp < 8; ++cp) {
        if ((cp & 1) == 0) {
            compC(A);
            if (cp + 2 < 8) loadC(A, cp + 2);
        } else {
            compC(B);
            if (cp + 2 < 8) loadC(B, cp + 2);
        }
    }

    // Cross-wave reduction (4 k-quarter partials) + fused scale/bias epilogue.
#pragma unroll
    for (int v = 0; v < 4; ++v) {
        red[wave * 512 + lane * 8 + v]     = acc0[v];
        red[wave * 512 + lane * 8 + 4 + v] = acc1[v];
    }
    __syncthreads();
#pragma unroll
    for (int pp = 0; pp < 2; ++pp) {
        const int p = tid + pp * 256;            // 0..511
        float s = red[p] + red[512 + p] + red[1024 + p] + red[1536 + p];
        const int pl   = p >> 3;                 // source lane
        const int r    = p & 7;
        const int half = r >> 2;                 // 0: tokens 0-15, 1: 16-31
        const int v    = r & 3;
        const int pn   = pl & 15;
        const int pq   = pl >> 4;
        const int token = half * 16 + pq * 4 + v;
        const int c = c0 + pn;
        out[(size_t)token * N + c] = s * scale[c] + bias[c];
    }
}

extern "C" void kernel_launch(void* const* d_in, const int* in_sizes, int n_in,
                              void* d_out, int out_size, void* d_ws, size_t ws_size,
                              hipStream_t stream) {
    const float* x     = (const float*)d_in[0];
    const int*   w     = (const int*)d_in[1];
    const float* scale = (const float*)d_in[2];
    const float* bias  = (const float*)d_in[3];
    float* out = (float*)d_out;

    unsigned short* xb = (unsigned short*)((char*)d_ws + XB_OFF);

    xcvt_kernel<<<dim3(64), dim3(256), 0, stream>>>(x, xb);
    w8gemm_kernel<<<dim3(N / 16), dim3(256), 0, stream>>>(
        (const __bf16*)xb, w, scale, bias, out);
}

// Round 6
// 367.987 us; speedup vs baseline: 1.0393x; 1.0393x over previous
//
#include <hip/hip_runtime.h>
#include <hip/hip_bf16.h>

// W8Linear: out[32,16384] = (x[32,4096] . W[16384,4096]^T) * scale[n] + bias[n]
// Harness dtype reality: x/scale/bias fp32 buffers (fp16 promoted); weight
// int32 (268 MB); out FLOAT32. Correct since R3 (absmax 2.0).
//
// FINAL (revert-to-best, R1 structure, 368.0 us measured).
//
// Complete falsification matrix for the ~2.2 TB/s weight-read rate
// (vs 6.7 TB/s pure-write fill and 5.9 TB/s L3-sourced in the same bench):
//   R7: k-phase de-lockstep                  -> null
//   R8: 4 KB contiguous runs                 -> null
//   R0: full-region linear, per-lane nt      -> regression (confounded)
//   R1: NT aux on global_load_lds            -> null  (THIS kernel, best)
//   R2: 1 blk/CU dbuf (256 streams)          -> null
//   R3: barrier-free direct-to-reg streaming -> null
//   R4: per-lane __builtin_nontemporal_load  -> null
// Conclusion: read-issue structure and cache policy are fully exonerated.
// The binding constraint is mandatory mixed DRAM traffic during our window:
// 268 MB cold weight read + ~256 MB dirty-line drain of the 1 GiB harness
// poison-fill (written immediately before us through the 256 MiB MALL).
// 524 MB combined / ~123 us = ~4.3 TB/s mixed-RW = normal DRAM efficiency;
// observed read-side 2.2 TB/s. Not kernel-addressable (both NT paths null).
// Floor: fill (~160 us, harness-owned) + restores + xcvt (~5 us) + GEMM at
// the mixed ceiling (~125-200 us) ~= 368 us total.

typedef __attribute__((ext_vector_type(4))) int    i32x4;
typedef __attribute__((ext_vector_type(4))) float  f32x4;
typedef __attribute__((ext_vector_type(8))) short  s16x8;
typedef __attribute__((ext_vector_type(8))) __bf16 bf16x8;

constexpr int K = 4096;
constexpr int N = 16384;
constexpr int BKI = 1024;                 // k-ints per tile (4 KB per row)
constexpr int NT = K / BKI;               // 4 tiles
constexpr int PITCH = 4096 + 16;          // LDS bytes per row (16B-aligned pad)
constexpr size_t XB_OFF = 0;              // bf16 x: 32*4096*2 = 256 KB in d_ws

// fp32 -> bf16 RNE (finite inputs).
__device__ inline unsigned short f2bf_rne(float f) {
    unsigned u = __builtin_bit_cast(unsigned, f);
    u += 0x7FFF + ((u >> 16) & 1);
    return (unsigned short)(u >> 16);
}

// 8 int32 weights -> 8 bf16, exact (|w|<=127; fp32->bf16 truncation lossless).
__device__ inline bf16x8 cvtW(i32x4 lo, i32x4 hi) {
    s16x8 r;
#pragma unroll
    for (int i = 0; i < 4; ++i) {
        r[i]     = (short)(__builtin_bit_cast(unsigned, (float)lo[i]) >> 16);
        r[i + 4] = (short)(__builtin_bit_cast(unsigned, (float)hi[i]) >> 16);
    }
    return __builtin_bit_cast(bf16x8, r);
}

// ---- k1: x fp32 -> bf16 ----------------------------------------------------
__global__ __launch_bounds__(256) void xcvt_kernel(const float* __restrict__ x,
                                                   unsigned short* __restrict__ xb) {
    const int i = (blockIdx.x * 256 + threadIdx.x) * 8;
    f32x4 lo = *reinterpret_cast<const f32x4*>(x + i);
    f32x4 hi = *reinterpret_cast<const f32x4*>(x + i + 4);
    s16x8 r;
#pragma unroll
    for (int j = 0; j < 4; ++j) {
        r[j]     = (short)f2bf_rne(lo[j]);
        r[j + 4] = (short)f2bf_rne(hi[j]);
    }
    *reinterpret_cast<s16x8*>(xb + i) = r;
}

// ---- k2: GEMM, 4 KB-contiguous-per-row staged tiles, NT weight reads -------
__global__ __launch_bounds__(256, 2) void w8gemm_kernel(
    const __bf16* __restrict__ xb,
    const int* __restrict__ w,
    const float* __restrict__ scale,
    const float* __restrict__ bias,
    float* __restrict__ out)
{
    extern __shared__ char smem[];   // 16 * PITCH = 65792 B

    const int tid  = threadIdx.x;
    const int lane = tid & 63;
    const int wave = tid >> 6;
    const int n16  = lane & 15;
    const int quad = lane >> 4;

    const int c0 = blockIdx.x * 16;       // 16 channels per block

    // Staging: wave w owns rows w*4..w*4+3; per tile, per row, 4 back-to-back
    // 1 KB global_load_lds -> 4 KB sequential in flight per row.
    auto stage = [&](int it) {
#pragma unroll
        for (int j = 0; j < 4; ++j) {
            const int row = wave * 4 + j;
            const char* gsrc = (const char*)(w + (size_t)(c0 + row) * K + it * BKI)
                               + (size_t)lane * 16;
            char* ldst = smem + row * PITCH + lane * 16;
#pragma unroll
            for (int s = 0; s < 4; ++s) {
                __builtin_amdgcn_global_load_lds(
                    (const __attribute__((address_space(1))) void*)(gsrc + s * 1024),
                    (__attribute__((address_space(3))) void*)(ldst + s * 1024),
                    16, 0, 2 /* NT */);
            }
        }
    };

    // Compute: wave w consumes k-ints [w*256, w*256+256) of each tile.
    // B fragment (16x16x32): row n16, ints quad*8..+7 -> 2 x b128 from LDS.
    const char* lrow = smem + n16 * PITCH + quad * 32 + wave * 1024;
    // A fragments from bf16 x (L2-hot): token n16 (acc0), n16+16 (acc1).
    const __bf16* __restrict__ xr0 = xb + (size_t)n16 * K + wave * 256 + quad * 8;
    const __bf16* __restrict__ xr1 = xr0 + (size_t)16 * K;

    f32x4 acc0 = {0.f, 0.f, 0.f, 0.f};
    f32x4 acc1 = {0.f, 0.f, 0.f, 0.f};

    stage(0);
#pragma unroll 1
    for (int it = 0; it < NT; ++it) {
        // Prefetch this tile's x fragments (8 k-steps x 2 halves x 16 B).
        bf16x8 aX0[8], aX1[8];
#pragma unroll
        for (int j = 0; j < 8; ++j) {
            const int off = it * BKI + j * 32;
            aX0[j] = *reinterpret_cast<const bf16x8*>(xr0 + off);
            aX1[j] = *reinterpret_cast<const bf16x8*>(xr1 + off);
        }
        __syncthreads();   // staging complete
#pragma unroll
        for (int j = 0; j < 8; ++j) {
            i32x4 b0 = *reinterpret_cast<const i32x4*>(lrow + j * 128);
            i32x4 b1 = *reinterpret_cast<const i32x4*>(lrow + j * 128 + 16);
            bf16x8 bf = cvtW(b0, b1);
            acc0 = __builtin_amdgcn_mfma_f32_16x16x32_bf16(aX0[j], bf, acc0, 0, 0, 0);
            acc1 = __builtin_amdgcn_mfma_f32_16x16x32_bf16(aX1[j], bf, acc1, 0, 0, 0);
        }
        __syncthreads();   // reads done before restaging the single buffer
        if (it + 1 < NT) stage(it + 1);
    }

    // Cross-wave reduction (4 k-quarter partials) + fused scale/bias epilogue.
    __syncthreads();
    float* red = (float*)smem;           // 4 waves x 512 floats = 8 KB
#pragma unroll
    for (int v = 0; v < 4; ++v) {
        red[wave * 512 + lane * 8 + v]     = acc0[v];
        red[wave * 512 + lane * 8 + 4 + v] = acc1[v];
    }
    __syncthreads();
#pragma unroll
    for (int pp = 0; pp < 2; ++pp) {
        const int p = tid + pp * 256;            // 0..511
        float s = red[p] + red[512 + p] + red[1024 + p] + red[1536 + p];
        const int pl   = p >> 3;                 // source lane
        const int r    = p & 7;
        const int half = r >> 2;                 // 0: tokens 0-15, 1: 16-31
        const int v    = r & 3;
        const int pn   = pl & 15;
        const int pq   = pl >> 4;
        const int token = half * 16 + pq * 4 + v;
        const int c = c0 + pn;
        out[(size_t)token * N + c] = s * scale[c] + bias[c];
    }
}

extern "C" void kernel_launch(void* const* d_in, const int* in_sizes, int n_in,
                              void* d_out, int out_size, void* d_ws, size_t ws_size,
                              hipStream_t stream) {
    const float* x     = (const float*)d_in[0];
    const int*   w     = (const int*)d_in[1];
    const float* scale = (const float*)d_in[2];
    const float* bias  = (const float*)d_in[3];
    float* out = (float*)d_out;

    unsigned short* xb = (unsigned short*)((char*)d_ws + XB_OFF);

    xcvt_kernel<<<dim3(64), dim3(256), 0, stream>>>(x, xb);
    w8gemm_kernel<<<dim3(N / 16), dim3(256), 16 * PITCH, stream>>>(
        (const __bf16*)xb, w, scale, bias, out);
}